// Round 8
// baseline (146.767 us; speedup 1.0000x reference)
//
#include <hip/hip_runtime.h>
#include <hip/hip_fp16.h>

#define UN 512

typedef __attribute__((ext_vector_type(8))) __bf16 bf16x8;
typedef __attribute__((ext_vector_type(4))) float f32x4;
typedef __attribute__((ext_vector_type(2))) __fp16 fp16x2;

// pack two fp32 into two bf16 (truncation; residual captured by pack_lo)
__device__ inline unsigned int pack_hi(float x0, float x1) {
    return __builtin_amdgcn_perm(__float_as_uint(x1), __float_as_uint(x0), 0x07060302u);
}
__device__ inline unsigned int pack_lo(float x0, float x1) {
    float h0 = __uint_as_float(__float_as_uint(x0) & 0xFFFF0000u);
    float h1 = __uint_as_float(__float_as_uint(x1) & 0xFFFF0000u);
    return __builtin_amdgcn_perm(__float_as_uint(x1 - h1), __float_as_uint(x0 - h0), 0x07060302u);
}
__device__ inline unsigned int pack_f16(float x, float y) {
    union { fp16x2 h; unsigned int u; } c;
    c.h = __builtin_amdgcn_cvt_pkrtz(x, y);
    return c.u;
}
__device__ inline float2 unpack_f16(unsigned int u) {
    union { unsigned int u32; __half2 h2; } c; c.u32 = u;
    return __half22float2(c.h2);
}

// ---------------------------------------------------------------------------
// Kernel 0 (grid 192): bid<128: transpose + bf16-split W -> WT_hi/lo[u][d].
//                      bid>=128: enc fp32 -> fp16 copy (for context phase).
// ---------------------------------------------------------------------------
__global__ __launch_bounds__(256) void prep_w(
    const float* __restrict__ Wenc, const float* __restrict__ Wdec,
    const float* __restrict__ enc,
    unsigned short* __restrict__ Weh, unsigned short* __restrict__ Wel,
    unsigned short* __restrict__ Wdh, unsigned short* __restrict__ Wdl,
    unsigned short* __restrict__ enc16)
{
    __shared__ float L[64][65];
    const int bid = blockIdx.x;
    const int t = threadIdx.x;
    if (bid >= 128) {                    // enc -> fp16
        const int blk = bid - 128;       // 0..63, 32 rows each
        const float* src = enc + (size_t)blk * 16384;
        unsigned int* dst = (unsigned int*)enc16 + (size_t)blk * 8192;
#pragma unroll 4
        for (int i = 0; i < 16; ++i) {
            int off = (i << 10) + (t << 2);
            float4 v = *(const float4*)(src + off);
            *(uint2*)(dst + (off >> 1)) =
                make_uint2(pack_f16(v.x, v.y), pack_f16(v.z, v.w));
        }
        return;
    }
    const float* W = (bid < 64) ? Wenc : Wdec;
    unsigned short* Th = (bid < 64) ? Weh : Wdh;
    unsigned short* Tl = (bid < 64) ? Wel : Wdl;
    const int tb = bid & 63;
    const int d0 = (tb >> 3) << 6, u0v = (tb & 7) << 6;
    {
        const int c4 = (t & 15) << 2;
#pragma unroll
        for (int i = 0; i < 4; ++i) {
            int row = (i << 4) + (t >> 4);
            float4 v = *(const float4*)&W[(size_t)(d0 + row) * 512 + u0v + c4];
            L[row][c4 + 0] = v.x;
            L[row][c4 + 1] = v.y;
            L[row][c4 + 2] = v.z;
            L[row][c4 + 3] = v.w;
        }
    }
    __syncthreads();
    const int u = t >> 2, dg = t & 3;
    unsigned int hw[8], lw[8];
#pragma unroll
    for (int j = 0; j < 8; ++j) {
        float x0 = L[(dg << 4) + (j << 1) + 0][u];
        float x1 = L[(dg << 4) + (j << 1) + 1][u];
        hw[j] = pack_hi(x0, x1);
        lw[j] = pack_lo(x0, x1);
    }
    size_t ob = (size_t)(u0v + u) * 512 + d0 + (dg << 4);
    *(uint4*)&Th[ob]     = make_uint4(hw[0], hw[1], hw[2], hw[3]);
    *(uint4*)&Th[ob + 8] = make_uint4(hw[4], hw[5], hw[6], hw[7]);
    *(uint4*)&Tl[ob]     = make_uint4(lw[0], lw[1], lw[2], lw[3]);
    *(uint4*)&Tl[ob + 8] = make_uint4(lw[4], lw[5], lw[6], lw[7]);
}

// ---------------------------------------------------------------------------
// Kernel 1 (grid 512): projections via split-bf16 MFMA, no LDS, no barriers,
// branchless 2-deep register prefetch. 2 blocks/CU.
//   bid<256 : enc proj, 64x64 tile -> d_encH fp16 (u-packed x4, *2log2e, +bias)
//   bid>=256: dec proj, 32x64 tile -> Gt4[b][q>>2][u][q&3] = 2^((dd+bias)*C)
// ---------------------------------------------------------------------------
__global__ __launch_bounds__(256) void proj_kernel(
    const float* __restrict__ enc, const float* __restrict__ dec,
    const unsigned short* __restrict__ Weh, const unsigned short* __restrict__ Wel,
    const unsigned short* __restrict__ Wdh, const unsigned short* __restrict__ Wdl,
    const float* __restrict__ bias_enc, const float* __restrict__ bias_dec,
    unsigned short* __restrict__ d_encH,  // [B][128][256][4] halves
    float* __restrict__ Gt4)              // [B][32][512][4]
{
    const float Cs = 2.8853900817779268f;   // 2*log2(e)
    const int bid = blockIdx.x;
    const int t = threadIdx.x;
    const int lane = t & 63, wv = t >> 6;
    const int frow = lane & 15, quad = lane >> 4;
    const int ko = quad << 3;

    if (bid < 256) {
        // ---------------- encoder projection ----------------
        const int wy = wv >> 1, wx = wv & 1;
        const int b = bid & 7, sub = bid >> 3;
        const int u0 = (sub >> 2) << 6, e0 = (sub & 3) << 6;
        const unsigned short *aph0, *apl0, *aph1, *apl1;
        {
            int r0 = u0 + (wy << 5) + frow;
            aph0 = Weh + (size_t)r0 * 512 + ko;  apl0 = Wel + (size_t)r0 * 512 + ko;
            aph1 = aph0 + 16 * 512;              apl1 = apl0 + 16 * 512;
        }
        const float *bp0, *bp1;
        {
            int r0 = (b << 8) + e0 + (wx << 5) + frow;
            bp0 = enc + (size_t)r0 * 512 + ko;
            bp1 = bp0 + 16 * 512;
        }
        struct EStage { bf16x8 ah0, ah1, al0, al1; float4 b00, b01, b10, b11; };
        auto LOADE = [&](int k) {
            EStage s;
            s.ah0 = *(const bf16x8*)(aph0 + k); s.al0 = *(const bf16x8*)(apl0 + k);
            s.ah1 = *(const bf16x8*)(aph1 + k); s.al1 = *(const bf16x8*)(apl1 + k);
            s.b00 = *(const float4*)(bp0 + k);  s.b01 = *(const float4*)(bp0 + k + 4);
            s.b10 = *(const float4*)(bp1 + k);  s.b11 = *(const float4*)(bp1 + k + 4);
            return s;
        };
        f32x4 acc[2][2] = {{{0.f,0.f,0.f,0.f},{0.f,0.f,0.f,0.f}},
                           {{0.f,0.f,0.f,0.f},{0.f,0.f,0.f,0.f}}};
        auto PROCE = [&](const EStage& s) {
            bf16x8 ah[2] = {s.ah0, s.ah1}, al[2] = {s.al0, s.al1};
            bf16x8 bh[2], bl[2];
            {
                union { unsigned int w[4]; bf16x8 v; } H, L;
                H.w[0] = pack_hi(s.b00.x, s.b00.y); H.w[1] = pack_hi(s.b00.z, s.b00.w);
                H.w[2] = pack_hi(s.b01.x, s.b01.y); H.w[3] = pack_hi(s.b01.z, s.b01.w);
                L.w[0] = pack_lo(s.b00.x, s.b00.y); L.w[1] = pack_lo(s.b00.z, s.b00.w);
                L.w[2] = pack_lo(s.b01.x, s.b01.y); L.w[3] = pack_lo(s.b01.z, s.b01.w);
                bh[0] = H.v; bl[0] = L.v;
                H.w[0] = pack_hi(s.b10.x, s.b10.y); H.w[1] = pack_hi(s.b10.z, s.b10.w);
                H.w[2] = pack_hi(s.b11.x, s.b11.y); H.w[3] = pack_hi(s.b11.z, s.b11.w);
                L.w[0] = pack_lo(s.b10.x, s.b10.y); L.w[1] = pack_lo(s.b10.z, s.b10.w);
                L.w[2] = pack_lo(s.b11.x, s.b11.y); L.w[3] = pack_lo(s.b11.z, s.b11.w);
                bh[1] = H.v; bl[1] = L.v;
            }
#pragma unroll
            for (int fm = 0; fm < 2; ++fm)
#pragma unroll
                for (int fn = 0; fn < 2; ++fn) {
                    acc[fm][fn] = __builtin_amdgcn_mfma_f32_16x16x32_bf16(ah[fm], bh[fn], acc[fm][fn], 0, 0, 0);
                    acc[fm][fn] = __builtin_amdgcn_mfma_f32_16x16x32_bf16(ah[fm], bl[fn], acc[fm][fn], 0, 0, 0);
                    acc[fm][fn] = __builtin_amdgcn_mfma_f32_16x16x32_bf16(al[fm], bh[fn], acc[fm][fn], 0, 0, 0);
                }
        };
        EStage sA = LOADE(0), sB = LOADE(32);
        for (int k0 = 0; k0 < 512; k0 += 64) {
            PROCE(sA); sA = LOADE((k0 + 64) & 511);
            PROCE(sB); sB = LOADE((k0 + 96) & 511);
        }
        // epilogue: C row = u (quad*4+reg), col = e (frow); fp16 store
#pragma unroll
        for (int fm = 0; fm < 2; ++fm)
#pragma unroll
            for (int fn = 0; fn < 2; ++fn) {
                int u_base = u0 + (wy << 5) + (fm << 4) + (quad << 2);
                int e      = e0 + (wx << 5) + (fn << 4) + frow;
                float4 bi = *(const float4*)&bias_enc[u_base];
                float o0 = (acc[fm][fn][0] + bi.x) * Cs;
                float o1 = (acc[fm][fn][1] + bi.y) * Cs;
                float o2 = (acc[fm][fn][2] + bi.z) * Cs;
                float o3 = (acc[fm][fn][3] + bi.w) * Cs;
                uint2* dst = (uint2*)d_encH +
                             (((size_t)((b << 7) + (u_base >> 2))) << 8) + e;
                *dst = make_uint2(pack_f16(o0, o1), pack_f16(o2, o3));
            }
    } else {
        // ---------------- decoder projection -> Gt4 ----------------
        const int bid2 = bid - 256;               // 0..255
        const int b  = bid2 & 7;
        const int rt = (bid2 >> 3) & 3;           // 32-row tile within batch
        const int ut = bid2 >> 5;                 // 0..7
        const int wy = wv >> 1, wx = wv & 1;      // wy: 16-row half, wx: 32-u half
        const int u0v = ut << 6;
        const float* ap0;
        {
            int r0 = (b << 7) + (rt << 5) + (wy << 4) + frow;
            ap0 = dec + (size_t)r0 * 512 + ko;
        }
        const unsigned short *bph0, *bpl0, *bph1, *bpl1;
        {
            int r0 = u0v + (wx << 5) + frow;
            bph0 = Wdh + (size_t)r0 * 512 + ko;  bpl0 = Wdl + (size_t)r0 * 512 + ko;
            bph1 = bph0 + 16 * 512;              bpl1 = bpl0 + 16 * 512;
        }
        struct DStage { float4 a0, a1; bf16x8 bh0, bh1, bl0, bl1; };
        auto LOADD = [&](int k) {
            DStage s;
            s.a0  = *(const float4*)(ap0 + k);  s.a1 = *(const float4*)(ap0 + k + 4);
            s.bh0 = *(const bf16x8*)(bph0 + k); s.bl0 = *(const bf16x8*)(bpl0 + k);
            s.bh1 = *(const bf16x8*)(bph1 + k); s.bl1 = *(const bf16x8*)(bpl1 + k);
            return s;
        };
        f32x4 acc[2] = {{0.f,0.f,0.f,0.f},{0.f,0.f,0.f,0.f}};
        auto PROCD = [&](const DStage& s) {
            bf16x8 ah, al;
            {
                union { unsigned int w[4]; bf16x8 v; } H, L;
                H.w[0] = pack_hi(s.a0.x, s.a0.y); H.w[1] = pack_hi(s.a0.z, s.a0.w);
                H.w[2] = pack_hi(s.a1.x, s.a1.y); H.w[3] = pack_hi(s.a1.z, s.a1.w);
                L.w[0] = pack_lo(s.a0.x, s.a0.y); L.w[1] = pack_lo(s.a0.z, s.a0.w);
                L.w[2] = pack_lo(s.a1.x, s.a1.y); L.w[3] = pack_lo(s.a1.z, s.a1.w);
                ah = H.v; al = L.v;
            }
            bf16x8 wh[2] = {s.bh0, s.bh1}, wl[2] = {s.bl0, s.bl1};
#pragma unroll
            for (int fn = 0; fn < 2; ++fn) {
                acc[fn] = __builtin_amdgcn_mfma_f32_16x16x32_bf16(ah, wh[fn], acc[fn], 0, 0, 0);
                acc[fn] = __builtin_amdgcn_mfma_f32_16x16x32_bf16(al, wh[fn], acc[fn], 0, 0, 0);
                acc[fn] = __builtin_amdgcn_mfma_f32_16x16x32_bf16(ah, wl[fn], acc[fn], 0, 0, 0);
            }
        };
        DStage sA = LOADD(0), sB = LOADD(32);
        for (int k0 = 0; k0 < 512; k0 += 64) {
            PROCD(sA); sA = LOADD((k0 + 64) & 511);
            PROCD(sB); sB = LOADD((k0 + 96) & 511);
        }
        // epilogue: rows=(b,q), cols=u; Gt4[b][q>>2][u][q&3] = 2^((dd+bias)*Cs)
        const int qb = (rt << 5) + (wy << 4) + (quad << 2);
#pragma unroll
        for (int fn = 0; fn < 2; ++fn) {
            int u = u0v + (wx << 5) + (fn << 4) + frow;
            float bi = bias_dec[u];
#pragma unroll
            for (int g = 0; g < 4; ++g) {
                int q = qb + g;
                Gt4[(((size_t)(b << 5) + (q >> 2)) << 11) + (u << 2) + (q & 3)] =
                    __builtin_amdgcn_exp2f((acc[fn][g] + bi) * Cs);
            }
        }
    }
}

// ---------------------------------------------------------------------------
// Kernel 2 (grid 256): fused scores + softmax + context.
// Score loop: de' fp16 vector loads (8B/lane); G/Wscore wave-uniform scalar
// loads; branchless 2-deep prefetch. Context reads fp16 enc copy, 1x, with
// LDS partial reduction.
// ---------------------------------------------------------------------------
__global__ __launch_bounds__(1024) void attend_kernel(
    const unsigned short* __restrict__ enc16,  // [B,256,512] halves
    const unsigned short* __restrict__ d_encH, // [B][128][256][4] halves
    const float* __restrict__ Gt4,             // [B][32][512][4]
    const float* __restrict__ Wscore,          // [512]
    float* __restrict__ out)                   // [B, 128, 512]
{
    __shared__ float smem[8192];         // score accs (16 KB) / ctx scratch (32 KB)
    __shared__ float wT[256][4];         // softmax weights [e][q]

    const float LOG2E = 1.4426950408889634f;

    const int bid = blockIdx.x;
    const int b = bid & 7;                      // XCD-local batch
    const int qt = (bid >> 3) & 31;
    const int q0 = qt << 2;
    const int tid = threadIdx.x;
    const int wv = tid >> 6, lane = tid & 63;

    // ---------------- scores ----------------
    const int e  = ((wv & 3) << 6) + lane;
    const int uq = wv >> 2;
    const int u0 = __builtin_amdgcn_readfirstlane(uq << 7);

    const float* Gb4 = Gt4 + (((size_t)(b << 5) + qt) << 11);
    const uint2* dptr8 = (const uint2*)d_encH +
                         (((size_t)(b << 7) + (u0 >> 2)) << 8) + e;

    float a0 = 0.f, a1 = 0.f, a2 = 0.f, a3 = 0.f;
    struct Stage { uint2 de; float4 g0, g1, g2, g3; float4 w; };
    auto LOADS = [&](int idx) {
        Stage s;
        s.de = dptr8[(size_t)idx << 8];
        int ub = u0 + (idx << 2);
        const float* gp = Gb4 + (ub << 2);
        s.g0 = *(const float4*)(gp);
        s.g1 = *(const float4*)(gp + 4);
        s.g2 = *(const float4*)(gp + 8);
        s.g3 = *(const float4*)(gp + 12);
        s.w  = *(const float4*)(Wscore + ub);
        return s;
    };
    auto PROCS = [&](const Stage& s) {
        float2 f01 = unpack_f16(s.de.x);
        float2 f23 = unpack_f16(s.de.y);
        float E;
        E = __builtin_amdgcn_exp2f(f01.x);
        a0 = fmaf(s.w.x, __builtin_amdgcn_rcpf(fmaf(E, s.g0.x, 1.f)), a0);
        a1 = fmaf(s.w.x, __builtin_amdgcn_rcpf(fmaf(E, s.g0.y, 1.f)), a1);
        a2 = fmaf(s.w.x, __builtin_amdgcn_rcpf(fmaf(E, s.g0.z, 1.f)), a2);
        a3 = fmaf(s.w.x, __builtin_amdgcn_rcpf(fmaf(E, s.g0.w, 1.f)), a3);
        E = __builtin_amdgcn_exp2f(f01.y);
        a0 = fmaf(s.w.y, __builtin_amdgcn_rcpf(fmaf(E, s.g1.x, 1.f)), a0);
        a1 = fmaf(s.w.y, __builtin_amdgcn_rcpf(fmaf(E, s.g1.y, 1.f)), a1);
        a2 = fmaf(s.w.y, __builtin_amdgcn_rcpf(fmaf(E, s.g1.z, 1.f)), a2);
        a3 = fmaf(s.w.y, __builtin_amdgcn_rcpf(fmaf(E, s.g1.w, 1.f)), a3);
        E = __builtin_amdgcn_exp2f(f23.x);
        a0 = fmaf(s.w.z, __builtin_amdgcn_rcpf(fmaf(E, s.g2.x, 1.f)), a0);
        a1 = fmaf(s.w.z, __builtin_amdgcn_rcpf(fmaf(E, s.g2.y, 1.f)), a1);
        a2 = fmaf(s.w.z, __builtin_amdgcn_rcpf(fmaf(E, s.g2.z, 1.f)), a2);
        a3 = fmaf(s.w.z, __builtin_amdgcn_rcpf(fmaf(E, s.g2.w, 1.f)), a3);
        E = __builtin_amdgcn_exp2f(f23.y);
        a0 = fmaf(s.w.w, __builtin_amdgcn_rcpf(fmaf(E, s.g3.x, 1.f)), a0);
        a1 = fmaf(s.w.w, __builtin_amdgcn_rcpf(fmaf(E, s.g3.y, 1.f)), a1);
        a2 = fmaf(s.w.w, __builtin_amdgcn_rcpf(fmaf(E, s.g3.z, 1.f)), a2);
        a3 = fmaf(s.w.w, __builtin_amdgcn_rcpf(fmaf(E, s.g3.w, 1.f)), a3);
    };
    Stage sA = LOADS(0), sB = LOADS(1);
    for (int g = 0; g < 32; g += 2) {
        PROCS(sA); sA = LOADS((g + 2) & 31);
        PROCS(sB); sB = LOADS((g + 3) & 31);
    }
    {
        float* accs = smem;                      // [uq][q][e]
        accs[((uq << 2) + 0) * 256 + e] = a0;
        accs[((uq << 2) + 1) * 256 + e] = a1;
        accs[((uq << 2) + 2) * 256 + e] = a2;
        accs[((uq << 2) + 3) * 256 + e] = a3;
    }
    __syncthreads();

    // ---------------- softmax over e per q ----------------
    if (wv < 4) {
        const float* accs = smem;
        const int q = wv;
        float l[4];
        float m = -1e30f;
#pragma unroll
        for (int i = 0; i < 4; ++i) {
            int ee = lane + (i << 6);
            float a = accs[(0 + q) * 256 + ee] + accs[(4 + q) * 256 + ee] +
                      accs[(8 + q) * 256 + ee] + accs[(12 + q) * 256 + ee];
            l[i] = -2.f * a;
            m = fmaxf(m, l[i]);
        }
#pragma unroll
        for (int mk = 32; mk >= 1; mk >>= 1) m = fmaxf(m, __shfl_xor(m, mk, 64));
        float p[4];
        float s = 0.f;
#pragma unroll
        for (int i = 0; i < 4; ++i) {
            p[i] = __builtin_amdgcn_exp2f((l[i] - m) * LOG2E);
            s += p[i];
        }
#pragma unroll
        for (int mk = 32; mk >= 1; mk >>= 1) s += __shfl_xor(s, mk, 64);
        float inv = __builtin_amdgcn_rcpf(s);
#pragma unroll
        for (int i = 0; i < 4; ++i) wT[lane + (i << 6)][q] = p[i] * inv;
    }
    __syncthreads();

    // ---------------- context (fp16 enc, 1x read) ----------------
    {
        const int dp = tid & 255;                // d-pair index
        const int d2 = dp << 1;
        float p0x = 0.f, p0y = 0.f, p1x = 0.f, p1y = 0.f;
        float p2x = 0.f, p2y = 0.f, p3x = 0.f, p3y = 0.f;
        const unsigned int* ep = (const unsigned int*)enc16 +
                                 (((size_t)(b << 8) + (uq << 6)) << 8) + dp;
#pragma unroll 4
        for (int ee = 0; ee < 64; ++ee) {
            float2 x = unpack_f16(ep[(size_t)ee << 8]);
            float4 w = *(const float4*)&wT[(uq << 6) + ee][0];   // wave-uniform
            p0x = fmaf(w.x, x.x, p0x); p0y = fmaf(w.x, x.y, p0y);
            p1x = fmaf(w.y, x.x, p1x); p1y = fmaf(w.y, x.y, p1y);
            p2x = fmaf(w.z, x.x, p2x); p2y = fmaf(w.z, x.y, p2y);
            p3x = fmaf(w.w, x.x, p3x); p3y = fmaf(w.w, x.y, p3y);
        }
        float2* sc = (float2*)smem;              // [eq][q][dp], 32 KB
        sc[((uq << 2) + 0) * 256 + dp] = make_float2(p0x, p0y);
        sc[((uq << 2) + 1) * 256 + dp] = make_float2(p1x, p1y);
        sc[((uq << 2) + 2) * 256 + dp] = make_float2(p2x, p2y);
        sc[((uq << 2) + 3) * 256 + dp] = make_float2(p3x, p3y);
        __syncthreads();
        const int q = uq;                        // tid>>8
        float2 s0 = sc[(0 + q) * 256 + dp];
        float2 s1 = sc[(4 + q) * 256 + dp];
        float2 s2 = sc[(8 + q) * 256 + dp];
        float2 s3 = sc[(12 + q) * 256 + dp];
        float2 o = make_float2(s0.x + s1.x + s2.x + s3.x,
                               s0.y + s1.y + s2.y + s3.y);
        *(float2*)&out[((size_t)((b << 7) + q0 + q) << 9) + d2] = o;
    }
}

// ---------------------------------------------------------------------------
extern "C" void kernel_launch(void* const* d_in, const int* in_sizes, int n_in,
                              void* d_out, int out_size, void* d_ws, size_t ws_size,
                              hipStream_t stream) {
    const float* enc      = (const float*)d_in[0];
    const float* dec      = (const float*)d_in[1];
    const float* Wenc     = (const float*)d_in[2];
    const float* Wdec     = (const float*)d_in[3];
    const float* Wscore   = (const float*)d_in[4];
    const float* bias_enc = (const float*)d_in[5];
    const float* bias_dec = (const float*)d_in[6];
    // d_in[7] = bias_score: constant shift, cancelled by softmax.
    float* out = (float*)d_out;

    float* ws = (float*)d_ws;
    unsigned short* d_encH = (unsigned short*)ws;          // 1,048,576 halves (2 MB)
    float* Gt4 = ws + 524288;                              // 524,288 floats (2 MB)
    unsigned short* Weh = (unsigned short*)(ws + 1048576); // 512 KB each
    unsigned short* Wel = Weh + 262144;
    unsigned short* Wdh = Wel + 262144;
    unsigned short* Wdl = Wdh + 262144;
    unsigned short* enc16 = Wdl + 262144;                  // 1,048,576 halves (2 MB)

    prep_w<<<192, 256, 0, stream>>>(Wenc, Wdec, enc, Weh, Wel, Wdh, Wdl, enc16);
    proj_kernel<<<512, 256, 0, stream>>>(enc, dec, Weh, Wel, Wdh, Wdl,
                                         bias_enc, bias_dec, d_encH, Gt4);
    attend_kernel<<<256, 1024, 0, stream>>>(enc16, d_encH, Gt4, Wscore, out);
}